// Round 1
// baseline (2867.072 us; speedup 1.0000x reference)
//
#include <hip/hip_runtime.h>
#include <stdint.h>

// ---------------------------------------------------------------------------
// GRU encoder (B=128,T=512,D=512,H=512,L=256), MI355X gfx950.
//
// R5: flag/poll protocol replaced by in-band sentinel ("self-announcing h").
//   h is bounded in [-1,1] (convex combo of tanh and previous h), so f2bf(h)
//   can never be the bf16 NaN pattern 0xFFFF. h lives in a 4-slot ring:
//     slot t%4   : h_t (read at iter t)
//     slot(t+1)%4: h_{t+1} (written, NO drain, at end of iter t)
//     slot(t+2)%4: re-sentineled (0xFFFF) at top of iter t by each cell's
//                  unique producer wave; the load_h16 vmcnt(0) of iter t
//                  orders sentinel before the iter-t+1 data store to the
//                  same cell (same wave -> program order + drain).
//   Readers-done proof for re-sentinel: wave at iter t observed complete
//   h_{t-1} => all 32 waves of its closed row-half community STORED h_{t-1}
//   => (program order) finished their iter t-2 reads of h_{t-2}, which is
//   exactly what slot (t+2)%4 holds. R=4 required (R=3 deadlocks laggards).
//   Consumer: retry load_h16 until no short == 0xFFFF (v_pk_max_u16 tree).
//   Critical path/step: ~store-propagate + 1-2 load RTTs (was ~4+ RTTs:
//   store-drain + flag propagate + poll RTTs + load).
//
// R5b: ig_gemm grid swapped to dim3(12,512) (bn fastest) so the 12 blocks
//   sharing one 256KB x-panel run temporally adjacent: x read ~once from
//   HBM instead of 12x (~1.6 GB -> ~130 MB); Wih (3MB) stays IF$-resident.
// ---------------------------------------------------------------------------

typedef short short8 __attribute__((ext_vector_type(8)));
typedef float f32x4 __attribute__((ext_vector_type(4)));
typedef int int4v __attribute__((ext_vector_type(4)));

#define NB 128
#define NT 512
#define ND 512
#define NH 512
#define NG 1536   // 3H
#define HSLOT (NB * NH)  // shorts per h ring slot (128 KB)

__device__ __forceinline__ unsigned short f2bf(float f) {
  union { float f; unsigned u; } v; v.f = f;
  unsigned r = v.u + 0x7fffu + ((v.u >> 16) & 1u);  // RNE
  return (unsigned short)(r >> 16);
}
__device__ __forceinline__ float bf2f(unsigned short u) {
  union { unsigned u; float f; } v; v.u = ((unsigned)u) << 16; return v.f;
}
__device__ __forceinline__ float sigmoid_f(float x) {
  float e = __builtin_amdgcn_exp2f(-1.4426950408889634f * x);
  return __builtin_amdgcn_rcpf(1.0f + e);
}
__device__ __forceinline__ float tanh_f(float x) {
  float e = __builtin_amdgcn_exp2f(2.8853900817779268f * x);
  return 1.0f - 2.0f * __builtin_amdgcn_rcpf(1.0f + e);
}
__device__ __forceinline__ short8 pack8(float4 a, float4 b) {
  short8 s;
  s[0] = (short)f2bf(a.x); s[1] = (short)f2bf(a.y);
  s[2] = (short)f2bf(a.z); s[3] = (short)f2bf(a.w);
  s[4] = (short)f2bf(b.x); s[5] = (short)f2bf(b.y);
  s[6] = (short)f2bf(b.z); s[7] = (short)f2bf(b.w);
  return s;
}

// 16 coherent 16B loads (this lane's A-fragments for K=512) + one drain.
// p must already include the per-quad `+ q*8` element offset.
__device__ __forceinline__ void load_h16(const unsigned short* p, int4v a[16]) {
  asm volatile(
      "global_load_dwordx4 %0,  %16, off sc0 sc1\n\t"
      "global_load_dwordx4 %1,  %16, off offset:64 sc0 sc1\n\t"
      "global_load_dwordx4 %2,  %16, off offset:128 sc0 sc1\n\t"
      "global_load_dwordx4 %3,  %16, off offset:192 sc0 sc1\n\t"
      "global_load_dwordx4 %4,  %16, off offset:256 sc0 sc1\n\t"
      "global_load_dwordx4 %5,  %16, off offset:320 sc0 sc1\n\t"
      "global_load_dwordx4 %6,  %16, off offset:384 sc0 sc1\n\t"
      "global_load_dwordx4 %7,  %16, off offset:448 sc0 sc1\n\t"
      "global_load_dwordx4 %8,  %16, off offset:512 sc0 sc1\n\t"
      "global_load_dwordx4 %9,  %16, off offset:576 sc0 sc1\n\t"
      "global_load_dwordx4 %10, %16, off offset:640 sc0 sc1\n\t"
      "global_load_dwordx4 %11, %16, off offset:704 sc0 sc1\n\t"
      "global_load_dwordx4 %12, %16, off offset:768 sc0 sc1\n\t"
      "global_load_dwordx4 %13, %16, off offset:832 sc0 sc1\n\t"
      "global_load_dwordx4 %14, %16, off offset:896 sc0 sc1\n\t"
      "global_load_dwordx4 %15, %16, off offset:960 sc0 sc1\n\t"
      "s_waitcnt vmcnt(0)"
      : "=&v"(a[0]), "=&v"(a[1]), "=&v"(a[2]), "=&v"(a[3]),
        "=&v"(a[4]), "=&v"(a[5]), "=&v"(a[6]), "=&v"(a[7]),
        "=&v"(a[8]), "=&v"(a[9]), "=&v"(a[10]), "=&v"(a[11]),
        "=&v"(a[12]), "=&v"(a[13]), "=&v"(a[14]), "=&v"(a[15])
      : "v"(p)
      : "memory");
}

// 4 coherent short stores (rows erow..erow+3, stride NH*2=1024B), NO drain:
// visibility is detected by consumers via the sentinel protocol.
__device__ __forceinline__ void store4_nodrain(unsigned short* p, unsigned v0,
                                               unsigned v1, unsigned v2, unsigned v3) {
  asm volatile(
      "global_store_short %0, %1, off sc0 sc1\n\t"
      "global_store_short %0, %2, off offset:1024 sc0 sc1\n\t"
      "global_store_short %0, %3, off offset:2048 sc0 sc1\n\t"
      "global_store_short %0, %4, off offset:3072 sc0 sc1"
      :
      : "v"(p), "v"(v0), "v"(v1), "v"(v2), "v"(v3)
      : "memory");
}

// Re-sentinel this wave's 4 cells (same addresses as its data stores).
__device__ __forceinline__ void sentinel4(unsigned short* p) {
  unsigned s = 0xFFFFu;
  asm volatile(
      "global_store_short %0, %1, off sc0 sc1\n\t"
      "global_store_short %0, %1, off offset:1024 sc0 sc1\n\t"
      "global_store_short %0, %1, off offset:2048 sc0 sc1\n\t"
      "global_store_short %0, %1, off offset:3072 sc0 sc1"
      :
      : "v"(p), "v"(s)
      : "memory");
}

__device__ __forceinline__ unsigned pkmax(unsigned a, unsigned b) {
  unsigned d;
  asm("v_pk_max_u16 %0, %1, %2" : "=v"(d) : "v"(a), "v"(b));
  return d;
}

// ---------------------------------------------------------------------------
// IG = x @ Wih^T + bias, bf16 out. M=65536, N=1536, K=512.
// Grid dim3(12,512): bn = blockIdx.x (fastest) so same-bm blocks co-run.
// ---------------------------------------------------------------------------
__global__ __launch_bounds__(256) void ig_gemm(
    const float* __restrict__ x, const float* __restrict__ Wih,
    const float* __restrict__ bias, unsigned short* __restrict__ IG) {
  __shared__ unsigned short As[128 * 40];
  __shared__ unsigned short Bs[128 * 40];
  const int tid = threadIdx.x;
  const int bn = blockIdx.x, bm = blockIdx.y;
  const int lane = tid & 63, w = tid >> 6;
  const int wm = w >> 1, wn = w & 1;
  const int l15 = lane & 15, q = lane >> 4;

  f32x4 acc[4][4] = {};

  for (int kt = 0; kt < 16; ++kt) {
    __syncthreads();
#pragma unroll
    for (int j = 0; j < 4; ++j) {
      int fi = tid + 256 * j;
      int row = fi >> 3, kq = fi & 7;
      float4 v = *(const float4*)(x + (size_t)(bm * 128 + row) * ND + kt * 32 + kq * 4);
      ushort4 s = {f2bf(v.x), f2bf(v.y), f2bf(v.z), f2bf(v.w)};
      *(ushort4*)&As[row * 40 + kq * 4] = s;
    }
#pragma unroll
    for (int j = 0; j < 4; ++j) {
      int fi = tid + 256 * j;
      int row = fi >> 3, kq = fi & 7;
      float4 v = *(const float4*)(Wih + (size_t)(bn * 128 + row) * ND + kt * 32 + kq * 4);
      ushort4 s = {f2bf(v.x), f2bf(v.y), f2bf(v.z), f2bf(v.w)};
      *(ushort4*)&Bs[row * 40 + kq * 4] = s;
    }
    __syncthreads();

    short8 af[4], bf[4];
#pragma unroll
    for (int tm = 0; tm < 4; ++tm)
      af[tm] = *(const short8*)&As[(wm * 64 + tm * 16 + l15) * 40 + q * 8];
#pragma unroll
    for (int tn = 0; tn < 4; ++tn)
      bf[tn] = *(const short8*)&Bs[(wn * 64 + tn * 16 + l15) * 40 + q * 8];
#pragma unroll
    for (int tm = 0; tm < 4; ++tm)
#pragma unroll
      for (int tn = 0; tn < 4; ++tn)
        acc[tm][tn] = __builtin_amdgcn_mfma_f32_16x16x32_bf16(af[tm], bf[tn], acc[tm][tn], 0, 0, 0);
  }

#pragma unroll
  for (int tm = 0; tm < 4; ++tm) {
#pragma unroll
    for (int tn = 0; tn < 4; ++tn) {
      int col = bn * 128 + wn * 64 + tn * 16 + l15;
      float bb = bias[col];
#pragma unroll
      for (int i = 0; i < 4; ++i) {
        int row = bm * 128 + wm * 64 + tm * 16 + q * 4 + i;
        IG[(size_t)row * NG + col] = f2bf(acc[tm][tn][i] + bb);
      }
    }
  }
}

// ---------------------------------------------------------------------------
// Persistent GRU recurrence. 64 blocks x 256 threads.
// block = (group g of 32 batch rows, chunk c of 32 h-cols).
// wave (wm,wn): rows [b0+wm*16, +16), cols [c*32+wn*16, +16).
// h exchange: 4-slot sentinel ring (see header comment).
// ---------------------------------------------------------------------------
template <bool USE_IG>
__global__ __launch_bounds__(256, 1) void gru_rec(
    const float* __restrict__ x, const float* __restrict__ Wih,
    const float* __restrict__ Whh, const float* __restrict__ bias,
    const float* __restrict__ bn, const unsigned short* __restrict__ IG,
    unsigned short* __restrict__ hbuf, float* __restrict__ hfin) {
  const int tid = threadIdx.x;
  const int lane = tid & 63;
  const int w = tid >> 6;
  const int wm = w >> 1, wn = w & 1;
  const int l15 = lane & 15, q = lane >> 4;
  const int g = blockIdx.x >> 4;   // 4 groups
  const int c = blockIdx.x & 15;   // 16 col-chunks of 32
  const int b0 = g * 32;
  const int col = c * 32 + wn * 16 + l15;  // this lane's h column
  const int mrow = b0 + wm * 16 + l15;     // A-fragment batch row
  const int erow = b0 + wm * 16 + q * 4;   // C-layout batch row base

  // Whh B-fragments -> registers: 3 gates x 16 k-chunks (192 VGPRs)
  short8 bfr[3][16];
#pragma unroll
  for (int gt = 0; gt < 3; ++gt) {
    const float* src = Whh + (size_t)(gt * NH + col) * NH + q * 8;
#pragma unroll
    for (int kk = 0; kk < 16; ++kk) {
      float4 v0 = *(const float4*)(src + kk * 32);
      float4 v1 = *(const float4*)(src + kk * 32 + 4);
      bfr[gt][kk] = pack8(v0, v1);
    }
  }

  float bi_r = 0.f, bi_z = 0.f, bi_n = 0.f;
  if (!USE_IG) {
    bi_r = bias[col];
    bi_z = bias[NH + col];
    bi_n = bias[2 * NH + col];
  }
  const float bnv = bn[col];

  float hreg[4] = {0.f, 0.f, 0.f, 0.f};

  for (int t = 0; t < NT; ++t) {
    const unsigned short* hcur = hbuf + (size_t)(t & 3) * HSLOT;
    unsigned short* hnxt  = hbuf + (size_t)((t + 1) & 3) * HSLOT;
    unsigned short* hsent = hbuf + (size_t)((t + 2) & 3) * HSLOT;

    // IG loads first (plain cached loads; latency overlaps h wait).
    float igr[4], igz[4], ign[4];
    if (USE_IG) {
#pragma unroll
      for (int i = 0; i < 4; ++i) {
        const size_t base = ((size_t)(erow + i) * NT + t) * NG + col;
        igr[i] = bf2f(IG[base]);
        igz[i] = bf2f(IG[base + NH]);
        ign[i] = bf2f(IG[base + 2 * NH]);
      }
    }

    // Re-sentinel my cells in slot t+2 (its previous readers provably done;
    // drained by this iter's load_h16 vmcnt(0) before my t+1 data store).
    sentinel4(hsent + (size_t)erow * NH + col);

    // Load h_t fragments; retry until no short is the 0xFFFF sentinel.
    int4v araw[16];
    {
      const unsigned short* hp = hcur + (size_t)mrow * NH + q * 8;
      for (;;) {
        load_h16(hp, araw);
        unsigned m0 = 0, m1 = 0, m2 = 0, m3 = 0;
#pragma unroll
        for (int kk = 0; kk < 16; ++kk) {
          m0 = pkmax(m0, (unsigned)araw[kk][0]);
          m1 = pkmax(m1, (unsigned)araw[kk][1]);
          m2 = pkmax(m2, (unsigned)araw[kk][2]);
          m3 = pkmax(m3, (unsigned)araw[kk][3]);
        }
        unsigned m = pkmax(pkmax(m0, m1), pkmax(m2, m3));
        int bad = (int)(((m & 0xFFFFu) == 0xFFFFu) | ((m >> 16) == 0xFFFFu));
        if (!__any(bad)) break;
      }
    }

    f32x4 ar = {0.f, 0.f, 0.f, 0.f};
    f32x4 az = {0.f, 0.f, 0.f, 0.f};
    f32x4 an = {0.f, 0.f, 0.f, 0.f};
    f32x4 ai = {0.f, 0.f, 0.f, 0.f};
#pragma unroll
    for (int kk = 0; kk < 16; ++kk) {
      short8 afk = __builtin_bit_cast(short8, araw[kk]);
      ar = __builtin_amdgcn_mfma_f32_16x16x32_bf16(afk, bfr[0][kk], ar, 0, 0, 0);
      az = __builtin_amdgcn_mfma_f32_16x16x32_bf16(afk, bfr[1][kk], az, 0, 0, 0);
      an = __builtin_amdgcn_mfma_f32_16x16x32_bf16(afk, bfr[2][kk], an, 0, 0, 0);
      if (!USE_IG) {
        const float* xp = x + ((size_t)mrow * NT + t) * ND + kk * 32 + q * 8;
        short8 xa = pack8(*(const float4*)xp, *(const float4*)(xp + 4));
#pragma unroll
        for (int gt = 0; gt < 3; ++gt) {
          const float* wp = Wih + (size_t)(gt * NH + col) * ND + kk * 32 + q * 8;
          short8 wf = pack8(*(const float4*)wp, *(const float4*)(wp + 4));
          if (gt == 0) ar = __builtin_amdgcn_mfma_f32_16x16x32_bf16(xa, wf, ar, 0, 0, 0);
          if (gt == 1) az = __builtin_amdgcn_mfma_f32_16x16x32_bf16(xa, wf, az, 0, 0, 0);
          if (gt == 2) ai = __builtin_amdgcn_mfma_f32_16x16x32_bf16(xa, wf, ai, 0, 0, 0);
        }
      }
    }

    // gates + h update; store via coherent short stores (no drain)
    unsigned sv[4];
#pragma unroll
    for (int i = 0; i < 4; ++i) {
      float xr = USE_IG ? (ar[i] + igr[i]) : (ar[i] + bi_r);
      float xz = USE_IG ? (az[i] + igz[i]) : (az[i] + bi_z);
      float xin = USE_IG ? ign[i] : (ai[i] + bi_n);
      float r = sigmoid_f(xr);
      float z = sigmoid_f(xz);
      float n = tanh_f(xin + r * (an[i] + bnv));
      float hn2 = (1.f - z) * n + z * hreg[i];
      hreg[i] = hn2;
      sv[i] = (unsigned)f2bf(hn2);
      if (t == NT - 1) hfin[(size_t)(erow + i) * NH + col] = hn2;
    }
    if (t != NT - 1) {
      store4_nodrain(hnxt + (size_t)erow * NH + col, sv[0], sv[1], sv[2], sv[3]);
    }
  }
}

// ---------------------------------------------------------------------------
// out = h_T @ Wlin^T + blin; mu = cols [0,256), logvar = cols [256,512).
// ---------------------------------------------------------------------------
__global__ __launch_bounds__(256) void final_linear(
    const float* __restrict__ hfin, const float* __restrict__ Wlin,
    const float* __restrict__ blin, float* __restrict__ out) {
  __shared__ float sh[16 * 516];
  const int tid = threadIdx.x;
  const int b0 = blockIdx.y * 16, o0 = blockIdx.x * 16;

  for (int j = tid; j < 16 * 128; j += 256) {
    int row = j >> 7, kq = j & 127;
    *(float4*)&sh[row * 516 + kq * 4] =
        *(const float4*)(hfin + (size_t)(b0 + row) * NH + kq * 4);
  }
  __syncthreads();

  const int bi = tid & 15, oi = tid >> 4;
  const int o = o0 + oi;
  const float4* wp = (const float4*)(Wlin + (size_t)o * NH);
  float4 a4 = {0.f, 0.f, 0.f, 0.f};
  for (int k4 = 0; k4 < 128; ++k4) {
    float4 wv = wp[k4];
    float4 hv = *(const float4*)&sh[bi * 516 + k4 * 4];
    a4.x += wv.x * hv.x; a4.y += wv.y * hv.y;
    a4.z += wv.z * hv.z; a4.w += wv.w * hv.w;
  }
  float v = a4.x + a4.y + a4.z + a4.w + blin[o];
  int b = b0 + bi;
  if (o < 256) out[b * 256 + o] = v;
  else out[32768 + b * 256 + (o - 256)] = v;
}

// ---------------------------------------------------------------------------
extern "C" void kernel_launch(void* const* d_in, const int* in_sizes, int n_in,
                              void* d_out, int out_size, void* d_ws, size_t ws_size,
                              hipStream_t stream) {
  const float* x    = (const float*)d_in[0];
  const float* Wih  = (const float*)d_in[1];
  const float* Whh  = (const float*)d_in[2];
  const float* bias = (const float*)d_in[3];
  const float* bn   = (const float*)d_in[4];
  const float* Wlin = (const float*)d_in[5];
  const float* blin = (const float*)d_in[6];
  float* out = (float*)d_out;

  char* ws = (char*)d_ws;
  // layout: [h ring 4*131072][hfin 262144][IG 201326592]
  unsigned short* hbuf = (unsigned short*)ws;
  float* hfin          = (float*)(ws + 4 * 131072);
  unsigned short* IG   = (unsigned short*)(ws + 4 * 131072 + 262144);
  const size_t need_min = 4 * 131072 + 262144;                       // 786432
  const size_t need_ig  = need_min + (size_t)NB * NT * NG * 2;        // ~202 MB
  if (ws_size < need_min) return;

  // slot 0 = h_0 = 0; slots 1..3 = 0xFFFF sentinel (graph-capture-safe)
  hipMemsetAsync(ws, 0, 131072, stream);
  hipMemsetAsync(ws + 131072, 0xFF, 3 * 131072, stream);

  const bool useIG = (ws_size >= need_ig);
  if (useIG) {
    ig_gemm<<<dim3(12, 512), 256, 0, stream>>>(x, Wih, bias, IG);
    gru_rec<true><<<64, 256, 0, stream>>>(x, Wih, Whh, bias, bn, IG, hbuf, hfin);
  } else {
    gru_rec<false><<<64, 256, 0, stream>>>(x, Wih, Whh, bias, bn, nullptr, hbuf, hfin);
  }
  final_linear<<<dim3(32, 8), 256, 0, stream>>>(hfin, Wlin, blin, out);
}

// Round 3
// 2329.549 us; speedup vs baseline: 1.2307x; 1.2307x over previous
//
#include <hip/hip_runtime.h>
#include <stdint.h>

// ---------------------------------------------------------------------------
// GRU encoder (B=128,T=512,D=512,H=512,L=256), MI355X gfx950.
//
// R7: drop R6's XCD handshake + scope demotion (hang risk; bench died).
// Keep the PROVEN R4 flag protocol, device scope everywhere, but fix the two
// measured cost drivers:
//   1) h-load redundancy: 32 blocks x 512 thr; block = 16 rows x 128 cols.
//      h_t[16x512] (16KB) loaded ONCE per block into LDS (coherent loads),
//      waves read A-fragments via swizzled ds_read_b128. Global h reads
//      drop 4MB/step -> 512KB/step.
//   2) poll contention: ONE flag per block (32 total), 4 polling lanes per
//      block (was 8192 lanes on 64 flags).
// Step: [wave0 lanes<4 poll 4 community flags >= t] -> bar -> coop fill LDS
//       -> bar -> ds_read frags + MFMA + gates -> store4+drain -> bar ->
//       tid0 flag = t+1.
// Induction (overwrite safety): flag[b]=t+1 => b stored h_{t+1} (drained)
// AND (program order) finished reading h_t. Writer overwrites slot of h_t
// only during iter t+1, after seeing all flags >= t+1. Same as R4.
// LDS swizzle: slot s of row holds global slot s^(row&7); reads XOR the
// same -> 2-way bank aliasing only (free, m136).
// ---------------------------------------------------------------------------

typedef short short8 __attribute__((ext_vector_type(8)));
typedef float f32x4 __attribute__((ext_vector_type(4)));
typedef int int4v __attribute__((ext_vector_type(4)));

#define NB 128
#define NT 512
#define ND 512
#define NH 512
#define NG 1536   // 3H
#define HSLOT (NB * NH)  // shorts per h slot (128 KB)

__device__ __forceinline__ unsigned short f2bf(float f) {
  union { float f; unsigned u; } v; v.f = f;
  unsigned r = v.u + 0x7fffu + ((v.u >> 16) & 1u);  // RNE
  return (unsigned short)(r >> 16);
}
__device__ __forceinline__ float bf2f(unsigned short u) {
  union { unsigned u; float f; } v; v.u = ((unsigned)u) << 16; return v.f;
}
__device__ __forceinline__ float sigmoid_f(float x) {
  float e = __builtin_amdgcn_exp2f(-1.4426950408889634f * x);
  return __builtin_amdgcn_rcpf(1.0f + e);
}
__device__ __forceinline__ float tanh_f(float x) {
  float e = __builtin_amdgcn_exp2f(2.8853900817779268f * x);
  return 1.0f - 2.0f * __builtin_amdgcn_rcpf(1.0f + e);
}
__device__ __forceinline__ short8 pack8(float4 a, float4 b) {
  short8 s;
  s[0] = (short)f2bf(a.x); s[1] = (short)f2bf(a.y);
  s[2] = (short)f2bf(a.z); s[3] = (short)f2bf(a.w);
  s[4] = (short)f2bf(b.x); s[5] = (short)f2bf(b.y);
  s[6] = (short)f2bf(b.z); s[7] = (short)f2bf(b.w);
  return s;
}

// two coherent 16B loads + one drain (LDS fill path)
__device__ __forceinline__ void load16x2_s(const unsigned short* p0,
                                           const unsigned short* p1,
                                           int4v* v0, int4v* v1) {
  asm volatile(
      "global_load_dwordx4 %0, %2, off sc0 sc1\n\t"
      "global_load_dwordx4 %1, %3, off sc0 sc1\n\t"
      "s_waitcnt vmcnt(0)"
      : "=&v"(*v0), "=&v"(*v1) : "v"(p0), "v"(p1) : "memory");
}

// 4 coherent short stores (rows erow..erow+3, stride 1024B) + drain so the
// subsequent flag store implies global visibility of this wave's slice.
__device__ __forceinline__ void store4_s(unsigned short* p, unsigned v0,
                                         unsigned v1, unsigned v2, unsigned v3) {
  asm volatile(
      "global_store_short %0, %1, off sc0 sc1\n\t"
      "global_store_short %0, %2, off offset:1024 sc0 sc1\n\t"
      "global_store_short %0, %3, off offset:2048 sc0 sc1\n\t"
      "global_store_short %0, %4, off offset:3072 sc0 sc1\n\t"
      "s_waitcnt vmcnt(0)"
      :: "v"(p), "v"(v0), "v"(v1), "v"(v2), "v"(v3) : "memory");
}

__device__ __forceinline__ unsigned poll_s(const unsigned* p) {
  unsigned f;
  asm volatile("global_load_dword %0, %1, off sc0 sc1\n\t"
               "s_waitcnt vmcnt(0)" : "=v"(f) : "v"(p) : "memory");
  return f;
}

__device__ __forceinline__ void fstore_s(unsigned* p, unsigned v) {
  asm volatile("global_store_dword %0, %1, off sc0 sc1"
               :: "v"(p), "v"(v) : "memory");
}

// ---------------------------------------------------------------------------
// IG = x @ Wih^T + bias, bf16 out. M=65536, N=1536, K=512.
// Grid dim3(12,512): bn fastest so the 12 blocks sharing one x-panel co-run
// (x read ~once from HBM instead of 12x).
// ---------------------------------------------------------------------------
__global__ __launch_bounds__(256) void ig_gemm(
    const float* __restrict__ x, const float* __restrict__ Wih,
    const float* __restrict__ bias, unsigned short* __restrict__ IG) {
  __shared__ unsigned short As[128 * 40];
  __shared__ unsigned short Bs[128 * 40];
  const int tid = threadIdx.x;
  const int bn = blockIdx.x, bm = blockIdx.y;
  const int lane = tid & 63, w = tid >> 6;
  const int wm = w >> 1, wn = w & 1;
  const int l15 = lane & 15, q = lane >> 4;

  f32x4 acc[4][4] = {};

  for (int kt = 0; kt < 16; ++kt) {
    __syncthreads();
#pragma unroll
    for (int j = 0; j < 4; ++j) {
      int fi = tid + 256 * j;
      int row = fi >> 3, kq = fi & 7;
      float4 v = *(const float4*)(x + (size_t)(bm * 128 + row) * ND + kt * 32 + kq * 4);
      ushort4 s = {f2bf(v.x), f2bf(v.y), f2bf(v.z), f2bf(v.w)};
      *(ushort4*)&As[row * 40 + kq * 4] = s;
    }
#pragma unroll
    for (int j = 0; j < 4; ++j) {
      int fi = tid + 256 * j;
      int row = fi >> 3, kq = fi & 7;
      float4 v = *(const float4*)(Wih + (size_t)(bn * 128 + row) * ND + kt * 32 + kq * 4);
      ushort4 s = {f2bf(v.x), f2bf(v.y), f2bf(v.z), f2bf(v.w)};
      *(ushort4*)&Bs[row * 40 + kq * 4] = s;
    }
    __syncthreads();

    short8 af[4], bf[4];
#pragma unroll
    for (int tm = 0; tm < 4; ++tm)
      af[tm] = *(const short8*)&As[(wm * 64 + tm * 16 + l15) * 40 + q * 8];
#pragma unroll
    for (int tn = 0; tn < 4; ++tn)
      bf[tn] = *(const short8*)&Bs[(wn * 64 + tn * 16 + l15) * 40 + q * 8];
#pragma unroll
    for (int tm = 0; tm < 4; ++tm)
#pragma unroll
      for (int tn = 0; tn < 4; ++tn)
        acc[tm][tn] = __builtin_amdgcn_mfma_f32_16x16x32_bf16(af[tm], bf[tn], acc[tm][tn], 0, 0, 0);
  }

#pragma unroll
  for (int tm = 0; tm < 4; ++tm) {
#pragma unroll
    for (int tn = 0; tn < 4; ++tn) {
      int col = bn * 128 + wn * 64 + tn * 16 + l15;
      float bb = bias[col];
#pragma unroll
      for (int i = 0; i < 4; ++i) {
        int row = bm * 128 + wm * 64 + tm * 16 + q * 4 + i;
        IG[(size_t)row * NG + col] = f2bf(acc[tm][tn][i] + bb);
      }
    }
  }
}

// ---------------------------------------------------------------------------
// Persistent GRU recurrence. 32 blocks x 512 threads.
// block: g = bid&7 (rows g*16..+16), cblk = bid>>3 (cols cblk*128..+128).
// wave w (0..7): 16 rows x 16 cols at col cblk*128 + w*16.
// flags[g*4 + cblk] = step count completed by that block.
// ---------------------------------------------------------------------------
template <bool USE_IG>
__global__ __launch_bounds__(512, 2) void gru_rec(
    const float* __restrict__ x, const float* __restrict__ Wih,
    const float* __restrict__ Whh, const float* __restrict__ bias,
    const float* __restrict__ bn, const unsigned short* __restrict__ IG,
    unsigned short* __restrict__ hbuf, unsigned* __restrict__ flags,
    float* __restrict__ hfin) {
  __shared__ unsigned short hs[16 * 512];  // h_t slab, swizzled (16 KB)

  const int tid = threadIdx.x;
  const int lane = tid & 63;
  const int w = tid >> 6;                  // 0..7
  const int l15 = lane & 15, q = lane >> 4;
  const int bid = blockIdx.x;
  const int g = bid & 7, cblk = bid >> 3;
  const int col = cblk * 128 + w * 16 + l15;  // this lane's h column
  const int erow = g * 16 + q * 4;            // C-layout batch row base
  const int mrow = g * 16 + l15;              // A-fragment batch row (!USE_IG path)

  unsigned* const myflag = flags + g * 4 + cblk;
  const unsigned* const pollbase = flags + g * 4;  // 4 community flags

  // Whh B-fragments -> registers: 3 gates x 16 k-chunks (192 VGPRs)
  short8 bfr[3][16];
#pragma unroll
  for (int gt = 0; gt < 3; ++gt) {
    const float* src = Whh + (size_t)(gt * NH + col) * NH + q * 8;
#pragma unroll
    for (int kk = 0; kk < 16; ++kk) {
      float4 v0 = *(const float4*)(src + kk * 32);
      float4 v1 = *(const float4*)(src + kk * 32 + 4);
      bfr[gt][kk] = pack8(v0, v1);
    }
  }

  float bi_r = 0.f, bi_z = 0.f, bi_n = 0.f;
  if (!USE_IG) {
    bi_r = bias[col];
    bi_z = bias[NH + col];
    bi_n = bias[2 * NH + col];
  }
  const float bnv = bn[col];

  float hreg[4] = {0.f, 0.f, 0.f, 0.f};

  // LDS fill indices (fixed per thread): 1024 16B-slots, 2 per thread.
  const int s0 = tid * 2;
  const int frow = s0 >> 6;        // 0..15
  const int fsi = s0 & 63;         // even
  const int fr7 = frow & 7;

  for (int t = 0; t < NT; ++t) {
    const unsigned short* hcur = hbuf + (size_t)(t & 1) * HSLOT;
    unsigned short* hnxt = hbuf + (size_t)((t & 1) ^ 1) * HSLOT;

    // IG loads first (plain cached loads; latency overlaps poll + fill).
    float igr[4], igz[4], ign[4];
    if (USE_IG) {
#pragma unroll
      for (int i = 0; i < 4; ++i) {
        const size_t base = ((size_t)(erow + i) * NT + t) * NG + col;
        igr[i] = bf2f(IG[base]);
        igz[i] = bf2f(IG[base + NH]);
        ign[i] = bf2f(IG[base + 2 * NH]);
      }
    }

    // wait for the 4 community blocks to have written h_t
    if (t > 0) {
      if (tid < 4) {
        const unsigned* fp = pollbase + tid;
        unsigned f = poll_s(fp);
        while ((int)f < t) f = poll_s(fp);
      }
      __syncthreads();
    }

    // cooperative fill: h_t[16x512] -> LDS, swizzled (slot s holds global
    // slot s^(row&7)), 32B per thread.
    {
      const unsigned short* hrow = hcur + (size_t)(g * 16 + frow) * NH;
      int4v v0, v1;
      load16x2_s(hrow + ((fsi ^ fr7) << 3), hrow + (((fsi + 1) ^ fr7) << 3),
                 &v0, &v1);
      *(int4v*)&hs[frow * 512 + (fsi << 3)] = v0;
      *(int4v*)&hs[frow * 512 + ((fsi + 1) << 3)] = v1;
    }
    __syncthreads();

    f32x4 ar = {0.f, 0.f, 0.f, 0.f};
    f32x4 az = {0.f, 0.f, 0.f, 0.f};
    f32x4 an = {0.f, 0.f, 0.f, 0.f};
    f32x4 ai = {0.f, 0.f, 0.f, 0.f};
    const int abase = l15 * 512;
    const int ar7 = (l15 & 7) << 3;
#pragma unroll
    for (int kk = 0; kk < 16; ++kk) {
      short8 afk = *(const short8*)&hs[abase + ((kk * 32 + q * 8) ^ ar7)];
      ar = __builtin_amdgcn_mfma_f32_16x16x32_bf16(afk, bfr[0][kk], ar, 0, 0, 0);
      az = __builtin_amdgcn_mfma_f32_16x16x32_bf16(afk, bfr[1][kk], az, 0, 0, 0);
      an = __builtin_amdgcn_mfma_f32_16x16x32_bf16(afk, bfr[2][kk], an, 0, 0, 0);
      if (!USE_IG) {
        const float* xp = x + ((size_t)mrow * NT + t) * ND + kk * 32 + q * 8;
        short8 xa = pack8(*(const float4*)xp, *(const float4*)(xp + 4));
#pragma unroll
        for (int gt = 0; gt < 3; ++gt) {
          const float* wp = Wih + (size_t)(gt * NH + col) * ND + kk * 32 + q * 8;
          short8 wf = pack8(*(const float4*)wp, *(const float4*)(wp + 4));
          if (gt == 0) ar = __builtin_amdgcn_mfma_f32_16x16x32_bf16(xa, wf, ar, 0, 0, 0);
          if (gt == 1) az = __builtin_amdgcn_mfma_f32_16x16x32_bf16(xa, wf, az, 0, 0, 0);
          if (gt == 2) ai = __builtin_amdgcn_mfma_f32_16x16x32_bf16(xa, wf, ai, 0, 0, 0);
        }
      }
    }

    // gates + h update; coherent stores + drain
    unsigned sv[4];
#pragma unroll
    for (int i = 0; i < 4; ++i) {
      float xr = USE_IG ? (ar[i] + igr[i]) : (ar[i] + bi_r);
      float xz = USE_IG ? (az[i] + igz[i]) : (az[i] + bi_z);
      float xin = USE_IG ? ign[i] : (ai[i] + bi_n);
      float r = sigmoid_f(xr);
      float z = sigmoid_f(xz);
      float n = tanh_f(xin + r * (an[i] + bnv));
      float hn2 = (1.f - z) * n + z * hreg[i];
      hreg[i] = hn2;
      sv[i] = (unsigned)f2bf(hn2);
      if (t == NT - 1) hfin[(size_t)(erow + i) * NH + col] = hn2;
    }
    if (t != NT - 1) {
      store4_s(hnxt + (size_t)erow * NH + col, sv[0], sv[1], sv[2], sv[3]);
      __syncthreads();  // all 8 waves' stores drained
      if (tid == 0) fstore_s(myflag, (unsigned)(t + 1));
    }
  }
}

// ---------------------------------------------------------------------------
// out = h_T @ Wlin^T + blin; mu = cols [0,256), logvar = cols [256,512).
// ---------------------------------------------------------------------------
__global__ __launch_bounds__(256) void final_linear(
    const float* __restrict__ hfin, const float* __restrict__ Wlin,
    const float* __restrict__ blin, float* __restrict__ out) {
  __shared__ float sh[16 * 516];
  const int tid = threadIdx.x;
  const int b0 = blockIdx.y * 16, o0 = blockIdx.x * 16;

  for (int j = tid; j < 16 * 128; j += 256) {
    int row = j >> 7, kq = j & 127;
    *(float4*)&sh[row * 516 + kq * 4] =
        *(const float4*)(hfin + (size_t)(b0 + row) * NH + kq * 4);
  }
  __syncthreads();

  const int bi = tid & 15, oi = tid >> 4;
  const int o = o0 + oi;
  const float4* wp = (const float4*)(Wlin + (size_t)o * NH);
  float4 a4 = {0.f, 0.f, 0.f, 0.f};
  for (int k4 = 0; k4 < 128; ++k4) {
    float4 wv = wp[k4];
    float4 hv = *(const float4*)&sh[bi * 516 + k4 * 4];
    a4.x += wv.x * hv.x; a4.y += wv.y * hv.y;
    a4.z += wv.z * hv.z; a4.w += wv.w * hv.w;
  }
  float v = a4.x + a4.y + a4.z + a4.w + blin[o];
  int b = b0 + bi;
  if (o < 256) out[b * 256 + o] = v;
  else out[32768 + b * 256 + (o - 256)] = v;
}

// ---------------------------------------------------------------------------
extern "C" void kernel_launch(void* const* d_in, const int* in_sizes, int n_in,
                              void* d_out, int out_size, void* d_ws, size_t ws_size,
                              hipStream_t stream) {
  const float* x    = (const float*)d_in[0];
  const float* Wih  = (const float*)d_in[1];
  const float* Whh  = (const float*)d_in[2];
  const float* bias = (const float*)d_in[3];
  const float* bn   = (const float*)d_in[4];
  const float* Wlin = (const float*)d_in[5];
  const float* blin = (const float*)d_in[6];
  float* out = (float*)d_out;

  char* ws = (char*)d_ws;
  // layout: [hbuf 262144][flags 1024][hfin 262144][IG 201326592]
  unsigned short* hbuf = (unsigned short*)ws;
  unsigned* flags      = (unsigned*)(ws + 262144);
  float* hfin          = (float*)(ws + 263168);
  unsigned short* IG   = (unsigned short*)(ws + 525312);
  const size_t need_min = 525312;
  const size_t need_ig  = need_min + (size_t)NB * NT * NG * 2;  // ~202 MB
  if (ws_size < need_min) return;

  // h slot0 = h_0 = 0; flags = 0 (graph-capture-safe)
  hipMemsetAsync(ws, 0, 131072, stream);
  hipMemsetAsync(ws + 262144, 0, 1024, stream);

  const bool useIG = (ws_size >= need_ig);
  if (useIG) {
    ig_gemm<<<dim3(12, 512), 256, 0, stream>>>(x, Wih, bias, IG);
    gru_rec<true><<<32, 512, 0, stream>>>(x, Wih, Whh, bias, bn, IG, hbuf, flags, hfin);
  } else {
    gru_rec<false><<<32, 512, 0, stream>>>(x, Wih, Whh, bias, bn, nullptr, hbuf, flags, hfin);
  }
  final_linear<<<dim3(32, 8), 256, 0, stream>>>(hfin, Wlin, blin, out);
}